// Round 1
// baseline (370.604 us; speedup 1.0000x reference)
//
#include <hip/hip_runtime.h>
#include <hip/hip_bf16.h>
#include <stdint.h>

// Problem constants (B=4, T=2048, D=256, M=128, L=16, P=2048)
#define TAU 0.35f   // bf16-path score uncertainty window for fp32 refinement

typedef __attribute__((ext_vector_type(8))) short bf16x8;
typedef __attribute__((ext_vector_type(4))) float f32x4;

__device__ __forceinline__ unsigned short f2bf(float f) {
  __bf16 h = (__bf16)f;                       // HW RNE convert (v_cvt_pk_bf16_f32)
  return __builtin_bit_cast(unsigned short, h);
}
__device__ __forceinline__ float bf2f(unsigned short u) {
  unsigned int v = ((unsigned int)u) << 16;
  return __builtin_bit_cast(float, v);
}
__device__ __forceinline__ void async_copy16(const void* g, void* l) {
  __builtin_amdgcn_global_load_lds(
      (const __attribute__((address_space(1))) unsigned int*)g,
      (__attribute__((address_space(3))) unsigned int*)l, 16, 0, 0);
}

// ---------------------------------------------------------------------------
// K0: transpose+convert x -> xt[b][d][t] (bf16, K-contig) ; w1 -> w1t[n][k]
//     (bf16, K-contig); zero njobs.
// ---------------------------------------------------------------------------
__global__ __launch_bounds__(256) void k_prep(
    const float* __restrict__ x, const float* __restrict__ w1,
    unsigned short* __restrict__ xt, unsigned short* __restrict__ w1t,
    int* __restrict__ njobs) {
  __shared__ float tileS[64][65];
  int bx = blockIdx.x, tid = threadIdx.x;
  if (bx == 0 && tid == 0) *njobs = 0;
  int j = tid & 63, i0 = tid >> 6;
  if (bx < 512) {                       // x tiles: b(4) * t-tiles(32) * d-tiles(4)
    int b = bx >> 7, t6 = (bx >> 2) & 31, d6 = bx & 3;
    const float* src = x + ((size_t)b * 2048 + (size_t)t6 * 64) * 256 + d6 * 64;
    for (int i = i0; i < 64; i += 4) tileS[i][j] = src[(size_t)i * 256 + j];
    __syncthreads();
    unsigned short* dst = xt + ((size_t)b * 256 + (size_t)d6 * 64) * 2048 + t6 * 64;
    for (int r = i0; r < 64; r += 4) dst[(size_t)r * 2048 + j] = f2bf(tileS[j][r]);
  } else {                              // w1 tiles: k-tiles(12) * n-tiles(4)
    int wt = bx - 512;
    int k6 = wt >> 2, n6 = wt & 3;
    const float* src = w1 + ((size_t)k6 * 64) * 256 + n6 * 64;
    for (int i = i0; i < 64; i += 4) tileS[i][j] = src[(size_t)i * 256 + j];
    __syncthreads();
    unsigned short* dst = w1t + ((size_t)n6 * 64) * 768 + k6 * 64;
    for (int r = i0; r < 64; r += 4) dst[(size_t)r * 768 + j] = f2bf(tileS[j][r]);
  }
}

// ---------------------------------------------------------------------------
// K1: head_rep/tail_rep = [head;tail] @ x  (bf16 MFMA, fp32 accum/out)
// Per batch: A = head|tail rows (4096 x 2048 fp32, converted inline),
// B = xt (K-contig bf16, staged via global_load_lds). 128x128 tile, BK=32.
// ---------------------------------------------------------------------------
__global__ __launch_bounds__(256) void k_gemm_rep(
    const float* __restrict__ head, const float* __restrict__ tail,
    const unsigned short* __restrict__ xt,
    float* __restrict__ head_rep, float* __restrict__ tail_rep) {
  __shared__ unsigned short As[128 * 32];  // fragment-order chunked layout
  __shared__ unsigned short Bs[128 * 32];  // row-major, 32 bf16 (64B) per row
  int bx = blockIdx.x;
  int b = bx >> 6, rem = bx & 63, mtile = rem >> 1, ntile = rem & 1;
  const float* Asrc = ((mtile < 16) ? head : tail) +
                      ((size_t)(b * 2048 + (mtile & 15) * 128)) * 2048;
  float* Crep = (mtile < 16) ? head_rep : tail_rep;
  const unsigned short* Bsrc = xt + ((size_t)(b * 256 + ntile * 128)) * 2048;

  int tid = threadIdx.x, lane = tid & 63, w = tid >> 6;

  // A staging: thread -> (row = tid>>1, half = tid&1), 16 floats per K-step
  int ar = tid >> 1, ah = tid & 1;
  bf16x8* aw0 = (bf16x8*)&As[(ar >> 4) * 512 + ((ah * 2 + 0) * 16 + (ar & 15)) * 8];
  bf16x8* aw1 = (bf16x8*)&As[(ar >> 4) * 512 + ((ah * 2 + 1) * 16 + (ar & 15)) * 8];

  // B staging (global_load_lds): 2 insts/wave, 16 rows x 4 chunks each
  const unsigned short* bg0 = Bsrc + (size_t)(w * 32 + (lane >> 2)) * 2048 + (lane & 3) * 8;
  const unsigned short* bg1 = bg0 + (size_t)16 * 2048;
  unsigned short* bl0 = &Bs[(w * 32 + 0) * 32];
  unsigned short* bl1 = &Bs[(w * 32 + 16) * 32];

  int wm = (w & 1) * 64, wn = (w >> 1) * 64;
  const bf16x8* afrag[4];
  const bf16x8* bfrag[4];
#pragma unroll
  for (int s = 0; s < 4; ++s) {
    afrag[s] = (const bf16x8*)&As[((w & 1) * 4 + s) * 512 + lane * 8];
    bfrag[s] = (const bf16x8*)&Bs[(wn + s * 16 + (lane & 15)) * 32 + (lane >> 4) * 8];
  }

  f32x4 acc[4][4];
#pragma unroll
  for (int i = 0; i < 4; ++i)
#pragma unroll
    for (int j = 0; j < 4; ++j) acc[i][j] = (f32x4){0.f, 0.f, 0.f, 0.f};

  float4 av[4];
  {
    const float4* ap = (const float4*)(Asrc + (size_t)ar * 2048 + ah * 16);
    av[0] = ap[0]; av[1] = ap[1]; av[2] = ap[2]; av[3] = ap[3];
  }

  for (int k0 = 0; k0 < 2048; k0 += 32) {
    __syncthreads();                 // everyone done reading previous tile
    async_copy16(bg0, bl0);
    async_copy16(bg1, bl1);
    bg0 += 32; bg1 += 32;
    bf16x8 p0, p1;
    p0[0] = (short)f2bf(av[0].x); p0[1] = (short)f2bf(av[0].y);
    p0[2] = (short)f2bf(av[0].z); p0[3] = (short)f2bf(av[0].w);
    p0[4] = (short)f2bf(av[1].x); p0[5] = (short)f2bf(av[1].y);
    p0[6] = (short)f2bf(av[1].z); p0[7] = (short)f2bf(av[1].w);
    p1[0] = (short)f2bf(av[2].x); p1[1] = (short)f2bf(av[2].y);
    p1[2] = (short)f2bf(av[2].z); p1[3] = (short)f2bf(av[2].w);
    p1[4] = (short)f2bf(av[3].x); p1[5] = (short)f2bf(av[3].y);
    p1[6] = (short)f2bf(av[3].z); p1[7] = (short)f2bf(av[3].w);
    *aw0 = p0; *aw1 = p1;
    // prefetch next K-step's A (latency overlaps MFMA below)
    int kn = k0 + 32;
    const float4* ap = (const float4*)(Asrc + (size_t)ar * 2048 +
                                       ((kn < 2048) ? (kn + ah * 16) : (ah * 16)));
    av[0] = ap[0]; av[1] = ap[1]; av[2] = ap[2]; av[3] = ap[3];
    __syncthreads();                 // drains vmcnt (async) + lgkm (ds_write)

    bf16x8 a_[4], b_[4];
#pragma unroll
    for (int s = 0; s < 4; ++s) { a_[s] = *afrag[s]; b_[s] = *bfrag[s]; }
#pragma unroll
    for (int i = 0; i < 4; ++i)
#pragma unroll
      for (int j = 0; j < 4; ++j)
        acc[i][j] = __builtin_amdgcn_mfma_f32_16x16x32_bf16(a_[i], b_[j], acc[i][j], 0, 0, 0);
  }

  // epilogue: C layout col=lane&15, row=(lane>>4)*4+i
  size_t rowbase = (size_t)(b * 2048 + (mtile & 15) * 128);
  int colbase = ntile * 128 + wn;
#pragma unroll
  for (int sm = 0; sm < 4; ++sm) {
    int row0 = wm + sm * 16 + ((lane >> 4) << 2);
#pragma unroll
    for (int sn = 0; sn < 4; ++sn) {
      int col = colbase + sn * 16 + (lane & 15);
#pragma unroll
      for (int i = 0; i < 4; ++i)
        Crep[(rowbase + row0 + i) * 256 + col] = acc[sm][sn][i];
    }
  }
}

// ---------------------------------------------------------------------------
// K2pre: featbf[p][0:256]=h, [256:512]=t, [512:768]=h*t  (bf16)
// ---------------------------------------------------------------------------
__global__ __launch_bounds__(256) void k_feat(
    const float* __restrict__ hrep, const float* __restrict__ trep,
    unsigned short* __restrict__ featbf) {
  int gid = blockIdx.x * 256 + threadIdx.x;  // 0..524287
  int p = gid >> 6, d0 = (gid & 63) * 4;
  float4 h4 = *(const float4*)&hrep[(size_t)p * 256 + d0];
  float4 t4 = *(const float4*)&trep[(size_t)p * 256 + d0];
  ushort4 a, bb, c;
  a.x = f2bf(h4.x); a.y = f2bf(h4.y); a.z = f2bf(h4.z); a.w = f2bf(h4.w);
  bb.x = f2bf(t4.x); bb.y = f2bf(t4.y); bb.z = f2bf(t4.z); bb.w = f2bf(t4.w);
  c.x = f2bf(h4.x * t4.x); c.y = f2bf(h4.y * t4.y);
  c.z = f2bf(h4.z * t4.z); c.w = f2bf(h4.w * t4.w);
  *(ushort4*)&featbf[(size_t)p * 768 + d0] = a;
  *(ushort4*)&featbf[(size_t)p * 768 + 256 + d0] = bb;
  *(ushort4*)&featbf[(size_t)p * 768 + 512 + d0] = c;
}

// ---------------------------------------------------------------------------
// K2: h = relu(feat @ w1 + b1) -> bf16.  M=8192,K=768,N=256. 64x128 tile.
// ---------------------------------------------------------------------------
__global__ __launch_bounds__(256) void k_gemm_mlp(
    const unsigned short* __restrict__ featbf, const unsigned short* __restrict__ w1t,
    const float* __restrict__ b1, unsigned short* __restrict__ hbf) {
  __shared__ unsigned short As[64 * 32];
  __shared__ unsigned short Bs[128 * 32];
  int bx = blockIdx.x, mtile = bx >> 1, ntile = bx & 1;
  int tid = threadIdx.x, lane = tid & 63, w = tid >> 6;
  const unsigned short* ag = featbf + ((size_t)(mtile * 64) + w * 16 + (lane >> 2)) * 768 + (lane & 3) * 8;
  const unsigned short* bg0 = w1t + ((size_t)(ntile * 128) + w * 32 + (lane >> 2)) * 768 + (lane & 3) * 8;
  const unsigned short* bg1 = bg0 + (size_t)16 * 768;
  unsigned short* al = &As[(w * 16) * 32];
  unsigned short* bl0 = &Bs[(w * 32) * 32];
  unsigned short* bl1 = &Bs[(w * 32 + 16) * 32];
  int wn = w * 32;
  const bf16x8* afr[4];
  const bf16x8* bfr[2];
#pragma unroll
  for (int s = 0; s < 4; ++s)
    afr[s] = (const bf16x8*)&As[(s * 16 + (lane & 15)) * 32 + (lane >> 4) * 8];
#pragma unroll
  for (int s = 0; s < 2; ++s)
    bfr[s] = (const bf16x8*)&Bs[((wn + s * 16) + (lane & 15)) * 32 + (lane >> 4) * 8];

  f32x4 acc[4][2];
#pragma unroll
  for (int i = 0; i < 4; ++i)
#pragma unroll
    for (int j = 0; j < 2; ++j) acc[i][j] = (f32x4){0.f, 0.f, 0.f, 0.f};

  for (int k0 = 0; k0 < 768; k0 += 32) {
    __syncthreads();
    async_copy16(ag, al); ag += 32;
    async_copy16(bg0, bl0); bg0 += 32;
    async_copy16(bg1, bl1); bg1 += 32;
    __syncthreads();
    bf16x8 a_[4], b_[2];
#pragma unroll
    for (int s = 0; s < 4; ++s) a_[s] = *afr[s];
#pragma unroll
    for (int s = 0; s < 2; ++s) b_[s] = *bfr[s];
#pragma unroll
    for (int i = 0; i < 4; ++i)
#pragma unroll
      for (int j = 0; j < 2; ++j)
        acc[i][j] = __builtin_amdgcn_mfma_f32_16x16x32_bf16(a_[i], b_[j], acc[i][j], 0, 0, 0);
  }
#pragma unroll
  for (int sm = 0; sm < 4; ++sm) {
    int row0 = mtile * 64 + sm * 16 + ((lane >> 4) << 2);
#pragma unroll
    for (int sn = 0; sn < 2; ++sn) {
      int col = ntile * 128 + wn + sn * 16 + (lane & 15);
      float bv = b1[col];
#pragma unroll
      for (int i = 0; i < 4; ++i) {
        float v = acc[sm][sn][i] + bv;
        hbf[(size_t)(row0 + i) * 256 + col] = f2bf(fmaxf(v, 0.f));
      }
    }
  }
}

// ---------------------------------------------------------------------------
// K3a: logits = h @ w2 + b2  (one wave per row, shuffle reduce)
// ---------------------------------------------------------------------------
__global__ __launch_bounds__(256) void k_logits(
    const unsigned short* __restrict__ hbf, const float* __restrict__ w2,
    const float* __restrict__ b2, float* __restrict__ logits) {
  int w = threadIdx.x >> 6, lane = threadIdx.x & 63;
  int p = blockIdx.x * 4 + w;
  ushort4 h4 = *(const ushort4*)&hbf[(size_t)p * 256 + lane * 4];
  float hv0 = bf2f(h4.x), hv1 = bf2f(h4.y), hv2 = bf2f(h4.z), hv3 = bf2f(h4.w);
  float4 wa = *(const float4*)&w2[lane * 8];
  float4 wb = *(const float4*)&w2[lane * 8 + 4];
  float s0 = hv0 * wa.x + hv1 * wa.z + hv2 * wb.x + hv3 * wb.z;
  float s1 = hv0 * wa.y + hv1 * wa.w + hv2 * wb.y + hv3 * wb.w;
#pragma unroll
  for (int off = 32; off; off >>= 1) { s0 += __shfl_xor(s0, off); s1 += __shfl_xor(s1, off); }
  if (lane == 0) { logits[(size_t)p * 2] = s0 + b2[0]; logits[(size_t)p * 2 + 1] = s1 + b2[1]; }
}

// ---------------------------------------------------------------------------
// K3b: per-mention top-1 + uncertainty set; emit refine jobs
// ---------------------------------------------------------------------------
__global__ void k_select(const float* __restrict__ logits, int* __restrict__ idxv,
                         float* __restrict__ mval, int* __restrict__ cmask,
                         int* __restrict__ njobs, int* __restrict__ jobs) {
  int q = blockIdx.x * 256 + threadIdx.x;
  if (q >= 512) return;
  int base = q * 16;  // == b*2048 + m*16 (flat pair index base)
  float s[16];
#pragma unroll
  for (int i = 0; i < 16; ++i) s[i] = logits[(size_t)(base + i) * 2 + 1];
  float best = s[0]; int bi = 0;
#pragma unroll
  for (int i = 1; i < 16; ++i) if (s[i] > best) { best = s[i]; bi = i; }
  int mask = 0, cnt = 0;
#pragma unroll
  for (int i = 0; i < 16; ++i) if (s[i] > best - TAU) { mask |= 1 << i; ++cnt; }
  idxv[q] = bi; mval[q] = best;
  if (cnt > 1) {
    cmask[q] = mask;
    for (int i = 0; i < 16; ++i)
      if ((mask >> i) & 1) { int j = atomicAdd(njobs, 1); jobs[j] = base + i; }
  } else cmask[q] = 0;
}

// ---------------------------------------------------------------------------
// K3c: fp32 exact score recompute for uncertain candidate pairs
// ---------------------------------------------------------------------------
__global__ __launch_bounds__(1024) void k_refine(
    const int* __restrict__ njobs, const int* __restrict__ jobs,
    const float* __restrict__ head, const float* __restrict__ tail,
    const float* __restrict__ x, const float* __restrict__ w1,
    const float* __restrict__ b1, const float* __restrict__ w2,
    const float* __restrict__ b2, float* __restrict__ refined) {
  __shared__ float hrow[2048], trow[2048], feat[768], red[1024], red2[1024];
  int tid = threadIdx.x, seg = tid >> 8, d = tid & 255;
  int nj = *njobs;
  for (int job = blockIdx.x; job < nj; job += gridDim.x) {
    int code = jobs[job];          // flat pair index b*2048+p
    int b = code >> 11, p = code & 2047;
    if (tid < 512)
      *(float4*)&hrow[tid * 4] = *(const float4*)&head[((size_t)(b * 2048 + p)) * 2048 + tid * 4];
    else {
      int u = tid - 512;
      *(float4*)&trow[u * 4] = *(const float4*)&tail[((size_t)(b * 2048 + p)) * 2048 + u * 4];
    }
    __syncthreads();
    float hr = 0.f, tr = 0.f;
    const float* xb = x + ((size_t)b * 2048) * 256 + d;
#pragma unroll 8
    for (int t = seg * 512; t < seg * 512 + 512; ++t) {
      float xv = xb[(size_t)t * 256];
      hr += hrow[t] * xv; tr += trow[t] * xv;
    }
    red[tid] = hr; red2[tid] = tr;
    __syncthreads();
    if (seg == 0) {
      float fh = red[d] + red[256 + d] + red[512 + d] + red[768 + d];
      float ft = red2[d] + red2[256 + d] + red2[512 + d] + red2[768 + d];
      feat[d] = fh; feat[256 + d] = ft; feat[512 + d] = fh * ft;
    }
    __syncthreads();
    float hp = 0.f;
    for (int ii = seg * 192; ii < seg * 192 + 192; ++ii) hp += feat[ii] * w1[(size_t)ii * 256 + d];
    red[tid] = hp;
    __syncthreads();
    if (seg == 0) {
      float hj = b1[d] + red[d] + red[256 + d] + red[512 + d] + red[768 + d];
      hj = fmaxf(hj, 0.f);
      red2[d] = hj * w2[d * 2 + 1];
    }
    __syncthreads();
    for (int s = 128; s > 0; s >>= 1) {
      if (tid < s) red2[tid] += red2[tid + s];
      __syncthreads();
    }
    if (tid == 0) refined[code] = red2[0] + b2[1];
    __syncthreads();
  }
}

// ---------------------------------------------------------------------------
// K4a: rep_m[q][d] = tail_rep[q*16+argmax][d] * max_val
// ---------------------------------------------------------------------------
__global__ __launch_bounds__(256) void k_repm(
    const int* __restrict__ idxv, const float* __restrict__ mval,
    const int* __restrict__ cmask, const float* __restrict__ refined,
    const float* __restrict__ trep, float* __restrict__ repm) {
  int q = blockIdx.x, d = threadIdx.x;
  int mask = cmask[q]; int bi; float v;
  if (mask) {
    bi = -1; v = -1e30f;
    for (int i = 0; i < 16; ++i)
      if ((mask >> i) & 1) { float s = refined[q * 16 + i]; if (s > v) { v = s; bi = i; } }
  } else { bi = idxv[q]; v = mval[q]; }
  repm[(size_t)q * 256 + d] = trep[((size_t)q * 16 + bi) * 256 + d] * v;
}

// ---------------------------------------------------------------------------
// K4b: out[b][t][d] = x[b][t][d] + sum_m cmp[b][m][t] * rep_m[b][m][d]
// ---------------------------------------------------------------------------
__global__ __launch_bounds__(256) void k_merge(
    const float* __restrict__ cmp, const float* __restrict__ repm,
    const float* __restrict__ x, float* __restrict__ out) {
  __shared__ float cl[128 * 32];
  int bx = blockIdx.x, b = bx >> 6, t0 = (bx & 63) * 32;
  int tid = threadIdx.x;
#pragma unroll
  for (int it = 0; it < 4; ++it) {
    int fidx = it * 256 + tid;
    int row = fidx >> 3, c4 = fidx & 7;
    *(float4*)&cl[row * 32 + c4 * 4] =
        *(const float4*)&cmp[((size_t)(b * 128 + row)) * 2048 + t0 + c4 * 4];
  }
  __syncthreads();
  int d = tid;
  float acc[32];
#pragma unroll
  for (int i = 0; i < 32; ++i) acc[i] = 0.f;
  for (int m = 0; m < 128; ++m) {
    float rv = repm[(size_t)(b * 128 + m) * 256 + d];
#pragma unroll
    for (int tt = 0; tt < 32; ++tt) acc[tt] += cl[m * 32 + tt] * rv;
  }
  const float* xb = x + ((size_t)(b * 2048 + t0)) * 256 + d;
  float* ob = out + ((size_t)(b * 2048 + t0)) * 256 + d;
  for (int tt = 0; tt < 32; ++tt) ob[(size_t)tt * 256] = xb[(size_t)tt * 256] + acc[tt];
}

// ---------------------------------------------------------------------------
// K5: masked KLDiv mean loss (single block)
// ---------------------------------------------------------------------------
__global__ __launch_bounds__(1024) void k_loss(
    const float* __restrict__ logits, const float* __restrict__ lab,
    const unsigned char* __restrict__ mask, float* __restrict__ out_loss) {
  __shared__ float rs[1024], rc[1024];
  int tid = threadIdx.x;
  float sum = 0.f, cnt = 0.f;
  for (int p = tid; p < 8192; p += 1024) {
    float l0 = logits[(size_t)p * 2], l1 = logits[(size_t)p * 2 + 1];
    float a0 = lab[(size_t)p * 2], a1 = lab[(size_t)p * 2 + 1];
    float mx = fmaxf(l0, l1);
    float lse = mx + logf(expf(l0 - mx) + expf(l1 - mx));
    float pw = 0.f;
    if (a0 > 0.f) pw += a0 * logf(fmaxf(a0, 1e-38f));
    if (a1 > 0.f) pw += a1 * logf(fmaxf(a1, 1e-38f));
    pw -= a0 * (l0 - lse) + a1 * (l1 - lse);
    if (mask[p]) { sum += pw; cnt += 1.f; }
  }
  rs[tid] = sum; rc[tid] = cnt;
  __syncthreads();
  for (int s = 512; s > 0; s >>= 1) {
    if (tid < s) { rs[tid] += rs[tid + s]; rc[tid] += rc[tid + s]; }
    __syncthreads();
  }
  if (tid == 0) *out_loss = rs[0] / (rc[0] * 2.0f);
}

// ---------------------------------------------------------------------------
extern "C" void kernel_launch(void* const* d_in, const int* in_sizes, int n_in,
                              void* d_out, int out_size, void* d_ws, size_t ws_size,
                              hipStream_t stream) {
  (void)in_sizes; (void)n_in; (void)out_size; (void)ws_size;
  const float* head = (const float*)d_in[0];
  const float* tail = (const float*)d_in[1];
  // d_in[2] = lens (uniform L=16) -- unused
  const float* x = (const float*)d_in[3];
  const float* cmp = (const float*)d_in[4];
  const float* lab = (const float*)d_in[5];
  const unsigned char* lmask = (const unsigned char*)d_in[6];
  const float* w1 = (const float*)d_in[7];
  const float* b1 = (const float*)d_in[8];
  const float* w2 = (const float*)d_in[9];
  const float* b2 = (const float*)d_in[10];
  float* out = (float*)d_out;

  char* ws = (char*)d_ws;
  size_t off = 0;
  auto alloc = [&](size_t bytes) -> void* {
    void* p = ws + off; off += (bytes + 255) & ~(size_t)255; return p;
  };
  unsigned short* xt = (unsigned short*)alloc(4ull * 256 * 2048 * 2);
  unsigned short* w1t = (unsigned short*)alloc(256ull * 768 * 2);
  float* hrep = (float*)alloc(8192ull * 256 * 4);
  float* trep = (float*)alloc(8192ull * 256 * 4);
  unsigned short* featb = (unsigned short*)alloc(8192ull * 768 * 2);
  unsigned short* hbf = (unsigned short*)alloc(8192ull * 256 * 2);
  float* logits = (float*)alloc(8192ull * 2 * 4);
  float* refined = (float*)alloc(8192ull * 4);
  int* idxv = (int*)alloc(512 * 4);
  float* mvalv = (float*)alloc(512 * 4);
  int* cmaskv = (int*)alloc(512 * 4);
  int* njobs = (int*)alloc(256);
  int* jobs = (int*)alloc(8192 * 4);
  float* repm = (float*)alloc(512ull * 256 * 4);

  k_prep<<<560, 256, 0, stream>>>(x, w1, xt, w1t, njobs);
  k_gemm_rep<<<256, 256, 0, stream>>>(head, tail, xt, hrep, trep);
  k_feat<<<2048, 256, 0, stream>>>(hrep, trep, featb);
  k_gemm_mlp<<<256, 256, 0, stream>>>(featb, w1t, b1, hbf);
  k_logits<<<2048, 256, 0, stream>>>(hbf, w2, b2, logits);
  k_select<<<2, 256, 0, stream>>>(logits, idxv, mvalv, cmaskv, njobs, jobs);
  k_refine<<<256, 1024, 0, stream>>>(njobs, jobs, head, tail, x, w1, b1, w2, b2, refined);
  k_repm<<<512, 256, 0, stream>>>(idxv, mvalv, cmaskv, refined, trep, repm);
  k_merge<<<256, 256, 0, stream>>>(cmp, repm, x, out);
  k_loss<<<1, 1024, 0, stream>>>(logits, lab, lmask, out + 4ull * 2048 * 256);
}

// Round 2
// 330.361 us; speedup vs baseline: 1.1218x; 1.1218x over previous
//
#include <hip/hip_runtime.h>
#include <hip/hip_bf16.h>
#include <stdint.h>

// Problem constants (B=4, T=2048, D=256, M=128, L=16, P=2048)
#define TAU 0.35f   // bf16-path score uncertainty window for fp32 refinement

typedef __attribute__((ext_vector_type(8))) short bf16x8;
typedef __attribute__((ext_vector_type(4))) float f32x4;

__device__ __forceinline__ unsigned short f2bf(float f) {
  __bf16 h = (__bf16)f;
  return __builtin_bit_cast(unsigned short, h);
}
__device__ __forceinline__ float bf2f(unsigned short u) {
  unsigned int v = ((unsigned int)u) << 16;
  return __builtin_bit_cast(float, v);
}
__device__ __forceinline__ void async_copy16(const void* g, void* l) {
  __builtin_amdgcn_global_load_lds(
      (const __attribute__((address_space(1))) unsigned int*)g,
      (__attribute__((address_space(3))) unsigned int*)l, 16, 0, 0);
}

// ---------------------------------------------------------------------------
// K0: transpose+convert x -> xt[b][d][t] (bf16, K-contig); w1 -> w1t[n][k]
//     (bf16, K-contig); init logits with b2; zero njobs.
// ---------------------------------------------------------------------------
__global__ __launch_bounds__(256) void k_prep(
    const float* __restrict__ x, const float* __restrict__ w1,
    const float* __restrict__ b2,
    unsigned short* __restrict__ xt, unsigned short* __restrict__ w1t,
    float* __restrict__ logits, int* __restrict__ njobs) {
  __shared__ float tileS[64][65];
  int bx = blockIdx.x, tid = threadIdx.x;
  if (bx == 0 && tid == 0) *njobs = 0;
  if (bx < 64) {  // logits init: 16384 floats
    int i = bx * 256 + tid;
    logits[i] = b2[i & 1];
  }
  int j = tid & 63, i0 = tid >> 6;
  if (bx < 512) {                       // x tiles: b(4) * t-tiles(32) * d-tiles(4)
    int b = bx >> 7, t6 = (bx >> 2) & 31, d6 = bx & 3;
    const float* src = x + ((size_t)b * 2048 + (size_t)t6 * 64) * 256 + d6 * 64;
    for (int i = i0; i < 64; i += 4) tileS[i][j] = src[(size_t)i * 256 + j];
    __syncthreads();
    unsigned short* dst = xt + ((size_t)b * 256 + (size_t)d6 * 64) * 2048 + t6 * 64;
    for (int r = i0; r < 64; r += 4) dst[(size_t)r * 2048 + j] = f2bf(tileS[j][r]);
  } else {                              // w1 tiles: k-tiles(12) * n-tiles(4)
    int wt = bx - 512;
    int k6 = wt >> 2, n6 = wt & 3;
    const float* src = w1 + ((size_t)k6 * 64) * 256 + n6 * 64;
    for (int i = i0; i < 64; i += 4) tileS[i][j] = src[(size_t)i * 256 + j];
    __syncthreads();
    unsigned short* dst = w1t + ((size_t)n6 * 64) * 768 + k6 * 64;
    for (int r = i0; r < 64; r += 4) dst[(size_t)r * 768 + j] = f2bf(tileS[j][r]);
  }
}

// ---------------------------------------------------------------------------
// K1: head_rep/tail_rep = [head;tail] @ x   (bf16 MFMA, fp32 out)
// 64x64 tiles, BK=64, double-buffered LDS, XOR-swizzled B layout.
// grid = 1024 (4 blocks/CU). blockIdx: ntile = bx>>8 (stride-256 siblings
// share an XCD under round-robin dispatch -> A fetched once from HBM).
// ---------------------------------------------------------------------------
__global__ __launch_bounds__(256, 4) void k_gemm_rep(
    const float* __restrict__ head, const float* __restrict__ tail,
    const unsigned short* __restrict__ xt,
    float* __restrict__ hrep, float* __restrict__ trep) {
  __shared__ unsigned short As[2][4096];  // 64 rows x 64 k, fragment-chunk order
  __shared__ unsigned short Bs[2][4096];  // chunk(col,k8) at col*8 + (k8^(col&7))
  int bx = blockIdx.x;
  int ntile = bx >> 8;              // 0..3
  int g = bx & 255;
  int b = g >> 6, mtile = g & 63;   // mtile<32: head, else tail
  const float* Asrc = ((mtile < 32) ? head : tail) +
                      ((size_t)(b * 2048 + (mtile & 31) * 64)) * 2048;
  float* Crep = (mtile < 32) ? hrep : trep;
  const unsigned short* Bsrc = xt + ((size_t)(b * 256 + ntile * 64)) * 2048;

  int tid = threadIdx.x, lane = tid & 63, w = tid >> 6;

  // ---- A staging (fp32 global -> regs -> convert -> ds_write) ----
  int arow = tid >> 2, akq = tid & 3;          // row 0..63, quarter 0..3
  const float* aptr = Asrc + (size_t)arow * 2048 + akq * 16;
  int rt = arow >> 4, r15 = arow & 15;
  int k8a = akq * 2, k8b = akq * 2 + 1;
  int awi0 = rt * 128 + (k8a >> 2) * 64 + (k8a & 3) * 16 + r15;  // chunk idx
  int awi1 = rt * 128 + (k8b >> 2) * 64 + (k8b & 3) * 16 + r15;

  // ---- B staging via global_load_lds (wave w stages cols w*16..w*16+15) ----
  const unsigned short* bg[2];
  int bdst[2];
#pragma unroll
  for (int a = 0; a < 2; ++a) {
    int colofs = a * 8 + (lane >> 3);
    int k8 = (lane & 7) ^ (colofs & 7);        // XOR swizzle
    bg[a] = Bsrc + (size_t)(w * 16 + colofs) * 2048 + k8 * 8;
    bdst[a] = (w * 128 + a * 64 + lane) * 8;   // ushort offset, lane-linear
  }

  // ---- fragment read indices ----
  int sw0 = (lane >> 4) ^ (lane & 7);          // kh=0 swizzled k8
  int sw1 = (4 + (lane >> 4)) ^ (lane & 7);    // kh=1
  int colc[4];
#pragma unroll
  for (int ct = 0; ct < 4; ++ct) colc[ct] = (ct * 16 + (lane & 15)) * 8;

  f32x4 acc[4];
#pragma unroll
  for (int ct = 0; ct < 4; ++ct) acc[ct] = (f32x4){0.f, 0.f, 0.f, 0.f};

  float4 av[4];
  {
    const float4* ap = (const float4*)aptr;
    av[0] = ap[0]; av[1] = ap[1]; av[2] = ap[2]; av[3] = ap[3];
  }
#pragma unroll
  for (int a = 0; a < 2; ++a) { async_copy16(bg[a], &Bs[0][bdst[a]]); bg[a] += 64; }
  {
    bf16x8 p0, p1;
    p0[0] = (short)f2bf(av[0].x); p0[1] = (short)f2bf(av[0].y);
    p0[2] = (short)f2bf(av[0].z); p0[3] = (short)f2bf(av[0].w);
    p0[4] = (short)f2bf(av[1].x); p0[5] = (short)f2bf(av[1].y);
    p0[6] = (short)f2bf(av[1].z); p0[7] = (short)f2bf(av[1].w);
    p1[0] = (short)f2bf(av[2].x); p1[1] = (short)f2bf(av[2].y);
    p1[2] = (short)f2bf(av[2].z); p1[3] = (short)f2bf(av[2].w);
    p1[4] = (short)f2bf(av[3].x); p1[5] = (short)f2bf(av[3].y);
    p1[6] = (short)f2bf(av[3].z); p1[7] = (short)f2bf(av[3].w);
    *(bf16x8*)&As[0][awi0 * 8] = p0;
    *(bf16x8*)&As[0][awi1 * 8] = p1;
  }
  {
    const float4* ap = (const float4*)(aptr + 64);
    av[0] = ap[0]; av[1] = ap[1]; av[2] = ap[2]; av[3] = ap[3];
  }
  __syncthreads();

  for (int it = 0; it < 32; ++it) {
    int cur = it & 1, nxt = cur ^ 1;
    if (it < 31) {
#pragma unroll
      for (int a = 0; a < 2; ++a) { async_copy16(bg[a], &Bs[nxt][bdst[a]]); bg[a] += 64; }
      bf16x8 p0, p1;
      p0[0] = (short)f2bf(av[0].x); p0[1] = (short)f2bf(av[0].y);
      p0[2] = (short)f2bf(av[0].z); p0[3] = (short)f2bf(av[0].w);
      p0[4] = (short)f2bf(av[1].x); p0[5] = (short)f2bf(av[1].y);
      p0[6] = (short)f2bf(av[1].z); p0[7] = (short)f2bf(av[1].w);
      p1[0] = (short)f2bf(av[2].x); p1[1] = (short)f2bf(av[2].y);
      p1[2] = (short)f2bf(av[2].z); p1[3] = (short)f2bf(av[2].w);
      p1[4] = (short)f2bf(av[3].x); p1[5] = (short)f2bf(av[3].y);
      p1[6] = (short)f2bf(av[3].z); p1[7] = (short)f2bf(av[3].w);
      *(bf16x8*)&As[nxt][awi0 * 8] = p0;
      *(bf16x8*)&As[nxt][awi1 * 8] = p1;
    }
    if (it < 30) {
      const float4* ap = (const float4*)(aptr + (it + 2) * 64);
      av[0] = ap[0]; av[1] = ap[1]; av[2] = ap[2]; av[3] = ap[3];
    }
    const unsigned short* A_ = As[cur];
    const unsigned short* B_ = Bs[cur];
    bf16x8 a0 = *(const bf16x8*)&A_[(w * 128 + lane) * 8];
    bf16x8 a1 = *(const bf16x8*)&A_[(w * 128 + 64 + lane) * 8];
#pragma unroll
    for (int ct = 0; ct < 4; ++ct) {
      bf16x8 b0 = *(const bf16x8*)&B_[(colc[ct] + sw0) * 8];
      acc[ct] = __builtin_amdgcn_mfma_f32_16x16x32_bf16(a0, b0, acc[ct], 0, 0, 0);
    }
#pragma unroll
    for (int ct = 0; ct < 4; ++ct) {
      bf16x8 b1 = *(const bf16x8*)&B_[(colc[ct] + sw1) * 8];
      acc[ct] = __builtin_amdgcn_mfma_f32_16x16x32_bf16(a1, b1, acc[ct], 0, 0, 0);
    }
    __syncthreads();
  }

  // epilogue: C layout col=lane&15, row=(lane>>4)*4+i
  size_t prow = (size_t)b * 2048 + (size_t)(mtile & 31) * 64 + w * 16 + ((lane >> 4) << 2);
  int cb = ntile * 64 + (lane & 15);
#pragma unroll
  for (int ct = 0; ct < 4; ++ct)
#pragma unroll
    for (int i = 0; i < 4; ++i)
      Crep[(prow + i) * 256 + cb + ct * 16] = acc[ct][i];
}

// ---------------------------------------------------------------------------
// K2pre: featbf[p][0:256]=h, [256:512]=t, [512:768]=h*t  (bf16)
// ---------------------------------------------------------------------------
__global__ __launch_bounds__(256) void k_feat(
    const float* __restrict__ hrep, const float* __restrict__ trep,
    unsigned short* __restrict__ featbf) {
  int gid = blockIdx.x * 256 + threadIdx.x;
  int p = gid >> 6, d0 = (gid & 63) * 4;
  float4 h4 = *(const float4*)&hrep[(size_t)p * 256 + d0];
  float4 t4 = *(const float4*)&trep[(size_t)p * 256 + d0];
  ushort4 a, bb, c;
  a.x = f2bf(h4.x); a.y = f2bf(h4.y); a.z = f2bf(h4.z); a.w = f2bf(h4.w);
  bb.x = f2bf(t4.x); bb.y = f2bf(t4.y); bb.z = f2bf(t4.z); bb.w = f2bf(t4.w);
  c.x = f2bf(h4.x * t4.x); c.y = f2bf(h4.y * t4.y);
  c.z = f2bf(h4.z * t4.z); c.w = f2bf(h4.w * t4.w);
  *(ushort4*)&featbf[(size_t)p * 768 + d0] = a;
  *(ushort4*)&featbf[(size_t)p * 768 + 256 + d0] = bb;
  *(ushort4*)&featbf[(size_t)p * 768 + 512 + d0] = c;
}

// ---------------------------------------------------------------------------
// K2: relu(feat @ w1 + b1) @ w2 + b2 -> logits (fused; atomicAdd partials).
// 64x64 tiles, BK=64, dbuf, all staging via global_load_lds (XOR swizzle).
// grid = 512 (2/CU). ntile = bx>>7 so siblings share XCD.
// ---------------------------------------------------------------------------
__global__ __launch_bounds__(256, 4) void k_gemm_mlp(
    const unsigned short* __restrict__ featb, const unsigned short* __restrict__ w1t,
    const float* __restrict__ b1, const float* __restrict__ w2,
    float* __restrict__ logits) {
  __shared__ unsigned short As[2][4096], Bs[2][4096];
  int bx = blockIdx.x;
  int ntile = bx >> 7;   // 0..3
  int mtile = bx & 127;  // 0..127
  int tid = threadIdx.x, lane = tid & 63, w = tid >> 6;

  const unsigned short* ag[2];
  const unsigned short* bgp[2];
  int dofs[2];
#pragma unroll
  for (int a = 0; a < 2; ++a) {
    int rowofs = a * 8 + (lane >> 3);
    int k8 = (lane & 7) ^ (rowofs & 7);
    ag[a] = featb + (size_t)(mtile * 64 + w * 16 + rowofs) * 768 + k8 * 8;
    bgp[a] = w1t + (size_t)(ntile * 64 + w * 16 + rowofs) * 768 + k8 * 8;
    dofs[a] = (w * 128 + a * 64 + lane) * 8;
  }
  int sw0 = (lane >> 4) ^ (lane & 7);
  int sw1 = (4 + (lane >> 4)) ^ (lane & 7);
  int arowc = (w * 16 + (lane & 15)) * 8;
  int colc[4];
#pragma unroll
  for (int ct = 0; ct < 4; ++ct) colc[ct] = (ct * 16 + (lane & 15)) * 8;

  f32x4 acc[4];
#pragma unroll
  for (int ct = 0; ct < 4; ++ct) acc[ct] = (f32x4){0.f, 0.f, 0.f, 0.f};

#pragma unroll
  for (int a = 0; a < 2; ++a) {
    async_copy16(ag[a], &As[0][dofs[a]]); ag[a] += 64;
    async_copy16(bgp[a], &Bs[0][dofs[a]]); bgp[a] += 64;
  }
  __syncthreads();

  for (int it = 0; it < 12; ++it) {
    int cur = it & 1, nxt = cur ^ 1;
    if (it < 11) {
#pragma unroll
      for (int a = 0; a < 2; ++a) {
        async_copy16(ag[a], &As[nxt][dofs[a]]); ag[a] += 64;
        async_copy16(bgp[a], &Bs[nxt][dofs[a]]); bgp[a] += 64;
      }
    }
    const unsigned short* A_ = As[cur];
    const unsigned short* B_ = Bs[cur];
    bf16x8 a0 = *(const bf16x8*)&A_[(arowc + sw0) * 8];
    bf16x8 a1 = *(const bf16x8*)&A_[(arowc + sw1) * 8];
#pragma unroll
    for (int ct = 0; ct < 4; ++ct) {
      bf16x8 b0 = *(const bf16x8*)&B_[(colc[ct] + sw0) * 8];
      acc[ct] = __builtin_amdgcn_mfma_f32_16x16x32_bf16(a0, b0, acc[ct], 0, 0, 0);
    }
#pragma unroll
    for (int ct = 0; ct < 4; ++ct) {
      bf16x8 b1 = *(const bf16x8*)&B_[(colc[ct] + sw1) * 8];
      acc[ct] = __builtin_amdgcn_mfma_f32_16x16x32_bf16(a1, b1, acc[ct], 0, 0, 0);
    }
    __syncthreads();
  }

  // epilogue: relu(+b1), dot with w2 cols, reduce over the 16-lane col group
  float bv[4], w20[4], w21[4];
#pragma unroll
  for (int ct = 0; ct < 4; ++ct) {
    int col = ntile * 64 + ct * 16 + (lane & 15);
    bv[ct] = b1[col]; w20[ct] = w2[col * 2]; w21[ct] = w2[col * 2 + 1];
  }
#pragma unroll
  for (int i = 0; i < 4; ++i) {
    float s0 = 0.f, s1 = 0.f;
#pragma unroll
    for (int ct = 0; ct < 4; ++ct) {
      float r = fmaxf(acc[ct][i] + bv[ct], 0.f);
      s0 += r * w20[ct]; s1 += r * w21[ct];
    }
#pragma unroll
    for (int off = 1; off < 16; off <<= 1) {
      s0 += __shfl_xor(s0, off); s1 += __shfl_xor(s1, off);
    }
    if ((lane & 15) == 0) {
      int row = mtile * 64 + w * 16 + ((lane >> 4) << 2) + i;
      atomicAdd(&logits[row * 2], s0);
      atomicAdd(&logits[row * 2 + 1], s1);
    }
  }
}

// ---------------------------------------------------------------------------
// K3b: per-mention top-1 + uncertainty set; emit refine jobs
// ---------------------------------------------------------------------------
__global__ void k_select(const float* __restrict__ logits, int* __restrict__ idxv,
                         float* __restrict__ mval, int* __restrict__ cmask,
                         int* __restrict__ njobs, int* __restrict__ jobs) {
  int q = blockIdx.x * 256 + threadIdx.x;
  if (q >= 512) return;
  int base = q * 16;
  float s[16];
#pragma unroll
  for (int i = 0; i < 16; ++i) s[i] = logits[(size_t)(base + i) * 2 + 1];
  float best = s[0]; int bi = 0;
#pragma unroll
  for (int i = 1; i < 16; ++i) if (s[i] > best) { best = s[i]; bi = i; }
  int mask = 0, cnt = 0;
#pragma unroll
  for (int i = 0; i < 16; ++i) if (s[i] > best - TAU) { mask |= 1 << i; ++cnt; }
  idxv[q] = bi; mval[q] = best;
  if (cnt > 1) {
    cmask[q] = mask;
    for (int i = 0; i < 16; ++i)
      if ((mask >> i) & 1) { int j = atomicAdd(njobs, 1); jobs[j] = base + i; }
  } else cmask[q] = 0;
}

// ---------------------------------------------------------------------------
// K3c: fp32 exact score recompute for uncertain candidate pairs
// ---------------------------------------------------------------------------
__global__ __launch_bounds__(1024) void k_refine(
    const int* __restrict__ njobs, const int* __restrict__ jobs,
    const float* __restrict__ head, const float* __restrict__ tail,
    const float* __restrict__ x, const float* __restrict__ w1,
    const float* __restrict__ b1, const float* __restrict__ w2,
    const float* __restrict__ b2, float* __restrict__ refined) {
  __shared__ float hrow[2048], trow[2048], feat[768], red[1024], red2[1024];
  int tid = threadIdx.x, seg = tid >> 8, d = tid & 255;
  int nj = *njobs;
  for (int job = blockIdx.x; job < nj; job += gridDim.x) {
    int code = jobs[job];
    int b = code >> 11, p = code & 2047;
    if (tid < 512)
      *(float4*)&hrow[tid * 4] = *(const float4*)&head[((size_t)(b * 2048 + p)) * 2048 + tid * 4];
    else {
      int u = tid - 512;
      *(float4*)&trow[u * 4] = *(const float4*)&tail[((size_t)(b * 2048 + p)) * 2048 + u * 4];
    }
    __syncthreads();
    float hr = 0.f, tr = 0.f;
    const float* xb = x + ((size_t)b * 2048) * 256 + d;
#pragma unroll 8
    for (int t = seg * 512; t < seg * 512 + 512; ++t) {
      float xv = xb[(size_t)t * 256];
      hr += hrow[t] * xv; tr += trow[t] * xv;
    }
    red[tid] = hr; red2[tid] = tr;
    __syncthreads();
    if (seg == 0) {
      float fh = red[d] + red[256 + d] + red[512 + d] + red[768 + d];
      float ft = red2[d] + red2[256 + d] + red2[512 + d] + red2[768 + d];
      feat[d] = fh; feat[256 + d] = ft; feat[512 + d] = fh * ft;
    }
    __syncthreads();
    float hp = 0.f;
    for (int ii = seg * 192; ii < seg * 192 + 192; ++ii) hp += feat[ii] * w1[(size_t)ii * 256 + d];
    red[tid] = hp;
    __syncthreads();
    if (seg == 0) {
      float hj = b1[d] + red[d] + red[256 + d] + red[512 + d] + red[768 + d];
      hj = fmaxf(hj, 0.f);
      red2[d] = hj * w2[d * 2 + 1];
    }
    __syncthreads();
    for (int s = 128; s > 0; s >>= 1) {
      if (tid < s) red2[tid] += red2[tid + s];
      __syncthreads();
    }
    if (tid == 0) refined[code] = red2[0] + b2[1];
    __syncthreads();
  }
}

// ---------------------------------------------------------------------------
// K4a: rep_m[q][d] = tail_rep[q*16+argmax][d] * max_val
// ---------------------------------------------------------------------------
__global__ __launch_bounds__(256) void k_repm(
    const int* __restrict__ idxv, const float* __restrict__ mval,
    const int* __restrict__ cmask, const float* __restrict__ refined,
    const float* __restrict__ trep, float* __restrict__ repm) {
  int q = blockIdx.x, d = threadIdx.x;
  int mask = cmask[q]; int bi; float v;
  if (mask) {
    bi = -1; v = -1e30f;
    for (int i = 0; i < 16; ++i)
      if ((mask >> i) & 1) { float s = refined[q * 16 + i]; if (s > v) { v = s; bi = i; } }
  } else { bi = idxv[q]; v = mval[q]; }
  repm[(size_t)q * 256 + d] = trep[((size_t)q * 16 + bi) * 256 + d] * v;
}

// ---------------------------------------------------------------------------
// K4b: out[b][t][d] = x + sum_m cmp[b][m][t] * rep_m[b][m][d]  (512 blocks)
// ---------------------------------------------------------------------------
__global__ __launch_bounds__(256) void k_merge(
    const float* __restrict__ cmp, const float* __restrict__ repm,
    const float* __restrict__ x, float* __restrict__ out) {
  __shared__ float cl[128 * 16];
  int bx = blockIdx.x, b = bx >> 7, t0 = (bx & 127) * 16;
  int tid = threadIdx.x;
#pragma unroll
  for (int it = 0; it < 2; ++it) {
    int f = it * 256 + tid;
    int row = f >> 2, c4 = (f & 3) * 4;
    *(float4*)&cl[row * 16 + c4] =
        *(const float4*)&cmp[((size_t)(b * 128 + row)) * 2048 + t0 + c4];
  }
  __syncthreads();
  float acc[16];
#pragma unroll
  for (int i = 0; i < 16; ++i) acc[i] = 0.f;
  int d = tid;
  for (int m = 0; m < 128; ++m) {
    float rv = repm[(size_t)(b * 128 + m) * 256 + d];
    const float4* c4p = (const float4*)&cl[m * 16];
#pragma unroll
    for (int jj = 0; jj < 4; ++jj) {
      float4 c = c4p[jj];
      acc[jj * 4] += c.x * rv; acc[jj * 4 + 1] += c.y * rv;
      acc[jj * 4 + 2] += c.z * rv; acc[jj * 4 + 3] += c.w * rv;
    }
  }
  const float* xb = x + ((size_t)(b * 2048 + t0)) * 256 + d;
  float* ob = out + ((size_t)(b * 2048 + t0)) * 256 + d;
#pragma unroll
  for (int tt = 0; tt < 16; ++tt) ob[(size_t)tt * 256] = xb[(size_t)tt * 256] + acc[tt];
}

// ---------------------------------------------------------------------------
// K5: masked KLDiv mean loss (single block)
// ---------------------------------------------------------------------------
__global__ __launch_bounds__(1024) void k_loss(
    const float* __restrict__ logits, const float* __restrict__ lab,
    const unsigned char* __restrict__ mask, float* __restrict__ out_loss) {
  __shared__ float rs[1024], rc[1024];
  int tid = threadIdx.x;
  float sum = 0.f, cnt = 0.f;
  for (int p = tid; p < 8192; p += 1024) {
    float l0 = logits[(size_t)p * 2], l1 = logits[(size_t)p * 2 + 1];
    float a0 = lab[(size_t)p * 2], a1 = lab[(size_t)p * 2 + 1];
    float mx = fmaxf(l0, l1);
    float lse = mx + logf(expf(l0 - mx) + expf(l1 - mx));
    float pw = 0.f;
    if (a0 > 0.f) pw += a0 * logf(fmaxf(a0, 1e-38f));
    if (a1 > 0.f) pw += a1 * logf(fmaxf(a1, 1e-38f));
    pw -= a0 * (l0 - lse) + a1 * (l1 - lse);
    if (mask[p]) { sum += pw; cnt += 1.f; }
  }
  rs[tid] = sum; rc[tid] = cnt;
  __syncthreads();
  for (int s = 512; s > 0; s >>= 1) {
    if (tid < s) { rs[tid] += rs[tid + s]; rc[tid] += rc[tid + s]; }
    __syncthreads();
  }
  if (tid == 0) *out_loss = rs[0] / (rc[0] * 2.0f);
}

// ---------------------------------------------------------------------------
extern "C" void kernel_launch(void* const* d_in, const int* in_sizes, int n_in,
                              void* d_out, int out_size, void* d_ws, size_t ws_size,
                              hipStream_t stream) {
  (void)in_sizes; (void)n_in; (void)out_size; (void)ws_size;
  const float* head = (const float*)d_in[0];
  const float* tail = (const float*)d_in[1];
  // d_in[2] = lens (uniform L=16) -- unused
  const float* x = (const float*)d_in[3];
  const float* cmp = (const float*)d_in[4];
  const float* lab = (const float*)d_in[5];
  const unsigned char* lmask = (const unsigned char*)d_in[6];
  const float* w1 = (const float*)d_in[7];
  const float* b1 = (const float*)d_in[8];
  const float* w2 = (const float*)d_in[9];
  const float* b2 = (const float*)d_in[10];
  float* out = (float*)d_out;

  char* ws = (char*)d_ws;
  size_t off = 0;
  auto alloc = [&](size_t bytes) -> void* {
    void* p = ws + off; off += (bytes + 255) & ~(size_t)255; return p;
  };
  unsigned short* xt = (unsigned short*)alloc(4ull * 256 * 2048 * 2);
  unsigned short* w1t = (unsigned short*)alloc(256ull * 768 * 2);
  float* hrep = (float*)alloc(8192ull * 256 * 4);
  float* trep = (float*)alloc(8192ull * 256 * 4);
  unsigned short* featb = (unsigned short*)alloc(8192ull * 768 * 2);
  float* logits = (float*)alloc(8192ull * 2 * 4);
  float* refined = (float*)alloc(8192ull * 4);
  int* idxv = (int*)alloc(512 * 4);
  float* mvalv = (float*)alloc(512 * 4);
  int* cmaskv = (int*)alloc(512 * 4);
  int* njobs = (int*)alloc(256);
  int* jobs = (int*)alloc(8192 * 4);
  float* repm = (float*)alloc(512ull * 256 * 4);

  k_prep<<<560, 256, 0, stream>>>(x, w1, b2, xt, w1t, logits, njobs);
  k_gemm_rep<<<1024, 256, 0, stream>>>(head, tail, xt, hrep, trep);
  k_feat<<<2048, 256, 0, stream>>>(hrep, trep, featb);
  k_gemm_mlp<<<512, 256, 0, stream>>>(featb, w1t, b1, w2, logits);
  k_select<<<2, 256, 0, stream>>>(logits, idxv, mvalv, cmaskv, njobs, jobs);
  k_refine<<<256, 1024, 0, stream>>>(njobs, jobs, head, tail, x, w1, b1, w2, b2, refined);
  k_repm<<<512, 256, 0, stream>>>(idxv, mvalv, cmaskv, refined, trep, repm);
  k_merge<<<512, 256, 0, stream>>>(cmp, repm, x, out);
  k_loss<<<1, 1024, 0, stream>>>(logits, lab, lmask, out + 4ull * 2048 * 256);
}